// Round 8
// baseline (69.371 us; speedup 1.0000x reference)
//
#include <hip/hip_runtime.h>

#define NPTS 1024
#define NN (NPTS * NPTS)
#define NEDGE 32768
#define INDIM 128
#define PAD 72

typedef __attribute__((ext_vector_type(8))) short bf16x8;
typedef __attribute__((ext_vector_type(4))) float f32x4;

__device__ inline ushort f2bf(float x) {
    union { float f; unsigned u; } v; v.f = x;
    unsigned r = (v.u + 0x7FFF + ((v.u >> 16) & 1)) >> 16;
    return (ushort)r;
}

#define MFMA(a, b, c) __builtin_amdgcn_mfma_f32_16x16x32_bf16(a, b, c, 0, 0, 0)

// ---------------- front-end kernels ----------------

// grid 1024 x 256: zero A; blocks 0..255 also compute p (one wave per node);
// last block zeroes dd.
__global__ void zeroA_p_kernel(float4* __restrict__ A4,
                               const float* __restrict__ feat,
                               const float* __restrict__ w,
                               const float* __restrict__ b,
                               float* __restrict__ p,
                               float4* __restrict__ dd4) {
    int t = threadIdx.x;
    A4[blockIdx.x * 256 + t] = make_float4(0.f, 0.f, 0.f, 0.f);
    if (blockIdx.x == 1023 && t < 256) dd4[t] = make_float4(0.f, 0.f, 0.f, 0.f);
    if (blockIdx.x < 256) {
        int wid = t >> 6, lane = t & 63;
        int node = blockIdx.x * 4 + wid;
        const float* f = feat + node * INDIM;
        float s = f[lane] * w[lane] + f[lane + 64] * w[lane + 64];
#pragma unroll
        for (int off = 32; off; off >>= 1) s += __shfl_down(s, off);
        if (lane == 0) p[node] = s + b[0];
    }
}

// scatter edges into A and accumulate degrees dd
__global__ void build_A_kernel(const int* __restrict__ eu, const int* __restrict__ ev,
                               const float* __restrict__ p, float* __restrict__ A,
                               float* __restrict__ dd) {
    int i = blockIdx.x * blockDim.x + threadIdx.x;
    if (i >= NEDGE) return;
    int u = eu[i], v = ev[i];
    float val = p[u] - p[v];
    if (val > 0.f) {
        float w = 1.f + val;
        atomicAdd(&A[u * NPTS + v], w);
        atomicAdd(&A[v * NPTS + u], w);
        atomicAdd(&dd[u], w);
        atomicAdd(&dd[v], w);
    } else {
        atomicAdd(&A[u * NPTS + u], 1.f);
        atomicAdd(&A[v * NPTS + v], 1.f);
        atomicAdd(&dd[u], 1.f);
        atomicAdd(&dd[v], 1.f);
    }
}

// T0 = I, T1 = M = -(dinv_i*(A+I)_ij*dinv_j), Mbf = bf16(M); dinv = rsqrt(dd+1)
__global__ void normalize_kernel(const float* __restrict__ A, const float* __restrict__ dd,
                                 float* __restrict__ out, ushort* __restrict__ Mbf) {
    int idx4 = blockIdx.x * blockDim.x + threadIdx.x;
    int i = idx4 >> 8;
    int j = (idx4 & 255) * 4;
    size_t idx = (size_t)idx4 * 4;
    float di = rsqrtf(dd[i] + 1.f);
    float4 a = *(const float4*)(A + idx);
    float4 d4 = *(const float4*)(dd + j);
    float4 t0 = make_float4(0.f, 0.f, 0.f, 0.f);
    if (i == j) t0.x = 1.f;
    else if (i == j + 1) t0.y = 1.f;
    else if (i == j + 2) t0.z = 1.f;
    else if (i == j + 3) t0.w = 1.f;
    a.x += (i == j);
    a.y += (i == j + 1);
    a.z += (i == j + 2);
    a.w += (i == j + 3);
    float4 m;
    m.x = -(di * a.x * rsqrtf(d4.x + 1.f));
    m.y = -(di * a.y * rsqrtf(d4.y + 1.f));
    m.z = -(di * a.z * rsqrtf(d4.z + 1.f));
    m.w = -(di * a.w * rsqrtf(d4.w + 1.f));
    *(float4*)(out + idx) = t0;
    *(float4*)(out + NN + idx) = m;
    ushort mb[4] = {f2bf(m.x), f2bf(m.y), f2bf(m.z), f2bf(m.w)};
    *(uint2*)(Mbf + idx) = *(uint2*)mb;
}

// ---------------- MFMA GEMMs ----------------
// 64x64 tile / block, 256 thr = 4 waves; wave owns 32x32 (2x2 of 16x16x32).
// LDS <= 27.6 KB -> 2 blocks/CU (launch_bounds(256,2)): two independent
// instruction streams per CU overlap each other's barrier/ds_read stalls.
// Proven 2-barrier K-loop: sync; ds_write; sync; global prefetch; MFMA.
// Staging: thread t loads row (t>>2), 16B chunks (t&3)*8 and (t&3)*8+32.

// phase 0: S = M*M -> T2 = 2S - I, Sbf = bf16(S)
__global__ __launch_bounds__(256, 2) void gemm_S_kernel(const ushort* __restrict__ Mbf,
                                                        ushort* __restrict__ Sbf,
                                                        float* __restrict__ out) {
    __shared__ __align__(16) ushort sA[64][PAD];
    __shared__ __align__(16) ushort sB[64][PAD];

    int tid = threadIdx.x;
    int brow = blockIdx.y * 64, bcol = blockIdx.x * 64;
    int r = tid >> 2, j0 = (tid & 3) * 8;
    int wid = tid >> 6, lane = tid & 63;
    int wr = (wid & 1) * 32, wc = (wid >> 1) * 32;
    int fr = lane & 15, g = lane >> 4;

    const ushort* Arow = Mbf + (size_t)(brow + r) * NPTS;
    const ushort* Brow = Mbf + (size_t)(bcol + r) * NPTS;

    f32x4 acc[2][2] = {};
    float4 pa0 = *(const float4*)(Arow + j0);
    float4 pa1 = *(const float4*)(Arow + 32 + j0);
    float4 pb0 = *(const float4*)(Brow + j0);
    float4 pb1 = *(const float4*)(Brow + 32 + j0);

    const int NT = NPTS / 64;
    for (int t = 0; t < NT; ++t) {
        __syncthreads();
        *(float4*)&sA[r][j0] = pa0;
        *(float4*)&sA[r][32 + j0] = pa1;
        *(float4*)&sB[r][j0] = pb0;
        *(float4*)&sB[r][32 + j0] = pb1;
        __syncthreads();
        if (t + 1 < NT) {
            int k0 = (t + 1) * 64;
            pa0 = *(const float4*)(Arow + k0 + j0);
            pa1 = *(const float4*)(Arow + k0 + 32 + j0);
            pb0 = *(const float4*)(Brow + k0 + j0);
            pb1 = *(const float4*)(Brow + k0 + 32 + j0);
        }
#pragma unroll
        for (int kc = 0; kc < 2; ++kc) {
            int kk = kc * 32 + g * 8;
            bf16x8 a0 = *(const bf16x8*)&sA[wr + fr][kk];
            bf16x8 a1 = *(const bf16x8*)&sA[wr + 16 + fr][kk];
            bf16x8 b0 = *(const bf16x8*)&sB[wc + fr][kk];
            bf16x8 b1 = *(const bf16x8*)&sB[wc + 16 + fr][kk];
            acc[0][0] = MFMA(a0, b0, acc[0][0]);
            acc[0][1] = MFMA(a0, b1, acc[0][1]);
            acc[1][0] = MFMA(a1, b0, acc[1][0]);
            acc[1][1] = MFMA(a1, b1, acc[1][1]);
        }
    }

    float* T2 = out + (size_t)2 * NN;
#pragma unroll
    for (int mi = 0; mi < 2; ++mi) {
#pragma unroll
        for (int ni = 0; ni < 2; ++ni) {
#pragma unroll
            for (int q = 0; q < 4; ++q) {
                int row = brow + wr + mi * 16 + g * 4 + q;
                int col = bcol + wc + ni * 16 + fr;
                size_t idx = (size_t)row * NPTS + col;
                float s = acc[mi][ni][q];
                T2[idx] = 2.f * s - (row == col ? 1.f : 0.f);
                Sbf[idx] = f2bf(s);
            }
        }
    }
}

// phase 1 (fused): P = S*S -> T4 = 8P - 4*T2 - 3I;  R = M*S -> T3 = 4R - 3*T1
__global__ __launch_bounds__(256, 2) void gemm_T34_kernel(const ushort* __restrict__ Mbf,
                                                          const ushort* __restrict__ Sbf,
                                                          float* __restrict__ out,
                                                          int zimag) {
    // hidden zeroing of the imag half (20.9 MB over 256 blocks)
    if (zimag) {
        int bid = blockIdx.y * 16 + blockIdx.x;
        float4* z = (float4*)(out + (size_t)5 * NN) + (size_t)bid * 5120 + threadIdx.x;
#pragma unroll
        for (int i = 0; i < 20; ++i) z[i * 256] = make_float4(0.f, 0.f, 0.f, 0.f);
    }

    __shared__ __align__(16) ushort sAS[64][PAD];
    __shared__ __align__(16) ushort sAM[64][PAD];
    __shared__ __align__(16) ushort sB[64][PAD];

    int tid = threadIdx.x;
    int brow = blockIdx.y * 64, bcol = blockIdx.x * 64;
    int r = tid >> 2, j0 = (tid & 3) * 8;
    int wid = tid >> 6, lane = tid & 63;
    int wr = (wid & 1) * 32, wc = (wid >> 1) * 32;
    int fr = lane & 15, g = lane >> 4;

    const ushort* ASrow = Sbf + (size_t)(brow + r) * NPTS;
    const ushort* AMrow = Mbf + (size_t)(brow + r) * NPTS;
    const ushort* Brow = Sbf + (size_t)(bcol + r) * NPTS;

    f32x4 accP[2][2] = {};
    f32x4 accR[2][2] = {};
    float4 ps0 = *(const float4*)(ASrow + j0);
    float4 ps1 = *(const float4*)(ASrow + 32 + j0);
    float4 pm0 = *(const float4*)(AMrow + j0);
    float4 pm1 = *(const float4*)(AMrow + 32 + j0);
    float4 pb0 = *(const float4*)(Brow + j0);
    float4 pb1 = *(const float4*)(Brow + 32 + j0);

    const int NT = NPTS / 64;
    for (int t = 0; t < NT; ++t) {
        __syncthreads();
        *(float4*)&sAS[r][j0] = ps0;
        *(float4*)&sAS[r][32 + j0] = ps1;
        *(float4*)&sAM[r][j0] = pm0;
        *(float4*)&sAM[r][32 + j0] = pm1;
        *(float4*)&sB[r][j0] = pb0;
        *(float4*)&sB[r][32 + j0] = pb1;
        __syncthreads();
        if (t + 1 < NT) {
            int k0 = (t + 1) * 64;
            ps0 = *(const float4*)(ASrow + k0 + j0);
            ps1 = *(const float4*)(ASrow + k0 + 32 + j0);
            pm0 = *(const float4*)(AMrow + k0 + j0);
            pm1 = *(const float4*)(AMrow + k0 + 32 + j0);
            pb0 = *(const float4*)(Brow + k0 + j0);
            pb1 = *(const float4*)(Brow + k0 + 32 + j0);
        }
#pragma unroll
        for (int kc = 0; kc < 2; ++kc) {
            int kk = kc * 32 + g * 8;
            bf16x8 b0 = *(const bf16x8*)&sB[wc + fr][kk];
            bf16x8 b1 = *(const bf16x8*)&sB[wc + 16 + fr][kk];
            bf16x8 s0 = *(const bf16x8*)&sAS[wr + fr][kk];
            bf16x8 s1 = *(const bf16x8*)&sAS[wr + 16 + fr][kk];
            accP[0][0] = MFMA(s0, b0, accP[0][0]);
            accP[0][1] = MFMA(s0, b1, accP[0][1]);
            accP[1][0] = MFMA(s1, b0, accP[1][0]);
            accP[1][1] = MFMA(s1, b1, accP[1][1]);
            bf16x8 m0 = *(const bf16x8*)&sAM[wr + fr][kk];
            bf16x8 m1 = *(const bf16x8*)&sAM[wr + 16 + fr][kk];
            accR[0][0] = MFMA(m0, b0, accR[0][0]);
            accR[0][1] = MFMA(m0, b1, accR[0][1]);
            accR[1][0] = MFMA(m1, b0, accR[1][0]);
            accR[1][1] = MFMA(m1, b1, accR[1][1]);
        }
    }

    float* T1 = out + (size_t)NN;
    float* T2 = out + (size_t)2 * NN;
    float* T3 = out + (size_t)3 * NN;
    float* T4 = out + (size_t)4 * NN;
#pragma unroll
    for (int mi = 0; mi < 2; ++mi) {
#pragma unroll
        for (int ni = 0; ni < 2; ++ni) {
#pragma unroll
            for (int q = 0; q < 4; ++q) {
                int row = brow + wr + mi * 16 + g * 4 + q;
                int col = bcol + wc + ni * 16 + fr;
                size_t idx = (size_t)row * NPTS + col;
                float sp = accP[mi][ni][q];
                float sr = accR[mi][ni][q];
                T4[idx] = 8.f * sp - 4.f * T2[idx] - (row == col ? 3.f : 0.f);
                T3[idx] = 4.f * sr - 3.f * T1[idx];
            }
        }
    }
}

__global__ void zero_kernel(float4* __restrict__ p, int n4) {
    int i = blockIdx.x * blockDim.x + threadIdx.x;
    if (i < n4) p[i] = make_float4(0.f, 0.f, 0.f, 0.f);
}

// ---------------- launch ----------------

extern "C" void kernel_launch(void* const* d_in, const int* in_sizes, int n_in,
                              void* d_out, int out_size, void* d_ws, size_t ws_size,
                              hipStream_t stream) {
    const float* feat = (const float*)d_in[0];
    const int* edges = (const int*)d_in[1];
    const float* w_e1 = (const float*)d_in[2];
    const float* b_e1 = (const float*)d_in[3];
    float* out = (float*)d_out;

    const size_t need = (size_t)NN * 4 + (size_t)NN * 2 + (size_t)NN * 2 + NPTS * 8 + 256;
    float* A;
    ushort* Mbf;
    ushort* Sbf;
    float* p;
    float* dd;
    int use_ws = (ws_size >= need);
    if (use_ws) {
        char* w = (char*)d_ws;
        A = (float*)w;        w += (size_t)NN * 4;
        Mbf = (ushort*)w;     w += (size_t)NN * 2;
        Sbf = (ushort*)w;     w += (size_t)NN * 2;
        p = (float*)w;        w += NPTS * 4;
        dd = (float*)w;
    } else {
        A = out + (size_t)5 * NN;
        Mbf = (ushort*)(out + (size_t)6 * NN);
        Sbf = Mbf + NN;
        p = out + (size_t)7 * NN;
        dd = p + NPTS;
    }

    zeroA_p_kernel<<<1024, 256, 0, stream>>>((float4*)A, feat, w_e1, b_e1, p, (float4*)dd);
    build_A_kernel<<<(NEDGE + 255) / 256, 256, 0, stream>>>(edges, edges + NEDGE, p, A, dd);
    normalize_kernel<<<NN / 4 / 256, 256, 0, stream>>>(A, dd, out, Mbf);

    dim3 grid(16, 16);
    gemm_S_kernel<<<grid, 256, 0, stream>>>(Mbf, Sbf, out);
    gemm_T34_kernel<<<grid, 256, 0, stream>>>(Mbf, Sbf, out, use_ws);

    if (!use_ws) {
        zero_kernel<<<(5 * NN / 4 + 255) / 256, 256, 0, stream>>>(
            (float4*)(out + (size_t)5 * NN), 5 * NN / 4);
    }
}

// Round 10
// 62.072 us; speedup vs baseline: 1.1176x; 1.1176x over previous
//
#include <hip/hip_runtime.h>

#define NPTS 1024
#define NN (NPTS * NPTS)
#define NEDGE 32768
#define INDIM 128
#define BKP 264  // 256 K + 8 pad (bf16 units)

typedef __attribute__((ext_vector_type(8))) short bf16x8;
typedef __attribute__((ext_vector_type(4))) float f32x4;

__device__ inline ushort f2bf(float x) {
    union { float f; unsigned u; } v; v.f = x;
    unsigned r = (v.u + 0x7FFF + ((v.u >> 16) & 1)) >> 16;
    return (ushort)r;
}

#define MFMA(a, b, c) __builtin_amdgcn_mfma_f32_16x16x32_bf16(a, b, c, 0, 0, 0)

// ---------------- front-end kernels ----------------

// grid 1024 x 256: zero A; blocks 0..255 also compute p (one wave per node);
// last block zeroes dd.
__global__ void zeroA_p_kernel(float4* __restrict__ A4,
                               const float* __restrict__ feat,
                               const float* __restrict__ w,
                               const float* __restrict__ b,
                               float* __restrict__ p,
                               float4* __restrict__ dd4) {
    int t = threadIdx.x;
    A4[blockIdx.x * 256 + t] = make_float4(0.f, 0.f, 0.f, 0.f);
    if (blockIdx.x == 1023 && t < 256) dd4[t] = make_float4(0.f, 0.f, 0.f, 0.f);
    if (blockIdx.x < 256) {
        int wid = t >> 6, lane = t & 63;
        int node = blockIdx.x * 4 + wid;
        const float* f = feat + node * INDIM;
        float s = f[lane] * w[lane] + f[lane + 64] * w[lane + 64];
#pragma unroll
        for (int off = 32; off; off >>= 1) s += __shfl_down(s, off);
        if (lane == 0) p[node] = s + b[0];
    }
}

// scatter edges into A and accumulate degrees dd
__global__ void build_A_kernel(const int* __restrict__ eu, const int* __restrict__ ev,
                               const float* __restrict__ p, float* __restrict__ A,
                               float* __restrict__ dd) {
    int i = blockIdx.x * blockDim.x + threadIdx.x;
    if (i >= NEDGE) return;
    int u = eu[i], v = ev[i];
    float val = p[u] - p[v];
    if (val > 0.f) {
        float w = 1.f + val;
        atomicAdd(&A[u * NPTS + v], w);
        atomicAdd(&A[v * NPTS + u], w);
        atomicAdd(&dd[u], w);
        atomicAdd(&dd[v], w);
    } else {
        atomicAdd(&A[u * NPTS + u], 1.f);
        atomicAdd(&A[v * NPTS + v], 1.f);
        atomicAdd(&dd[u], 1.f);
        atomicAdd(&dd[v], 1.f);
    }
}

// T0 = I, T1 = M = -(dinv_i*(A+I)_ij*dinv_j), Mbf = bf16(M); dinv = rsqrt(dd+1)
__global__ void normalize_kernel(const float* __restrict__ A, const float* __restrict__ dd,
                                 float* __restrict__ out, ushort* __restrict__ Mbf) {
    int idx4 = blockIdx.x * blockDim.x + threadIdx.x;
    int i = idx4 >> 8;
    int j = (idx4 & 255) * 4;
    size_t idx = (size_t)idx4 * 4;
    float di = rsqrtf(dd[i] + 1.f);
    float4 a = *(const float4*)(A + idx);
    float4 d4 = *(const float4*)(dd + j);
    float4 t0 = make_float4(0.f, 0.f, 0.f, 0.f);
    if (i == j) t0.x = 1.f;
    else if (i == j + 1) t0.y = 1.f;
    else if (i == j + 2) t0.z = 1.f;
    else if (i == j + 3) t0.w = 1.f;
    a.x += (i == j);
    a.y += (i == j + 1);
    a.z += (i == j + 2);
    a.w += (i == j + 3);
    float4 m;
    m.x = -(di * a.x * rsqrtf(d4.x + 1.f));
    m.y = -(di * a.y * rsqrtf(d4.y + 1.f));
    m.z = -(di * a.z * rsqrtf(d4.z + 1.f));
    m.w = -(di * a.w * rsqrtf(d4.w + 1.f));
    *(float4*)(out + idx) = t0;
    *(float4*)(out + NN + idx) = m;
    ushort mb[4] = {f2bf(m.x), f2bf(m.y), f2bf(m.z), f2bf(m.w)};
    *(uint2*)(Mbf + idx) = *(uint2*)mb;
}

// ---------------- MFMA GEMMs ----------------
// 64x64 tile / block, 1024 thr = 16 waves (4 waves/SIMD). Split-K 4-way:
// BK=256 staged per iteration; K-group gid=wid>>2 consumes K-slice
// [gid*64, gid*64+64). Wave w4=wid&3 owns 32x32 (2x2 of 16x16x32).
// Only 4 K-iterations x 2 barriers. Partials combined via LDS.
// ALL LDS regions carved from ONE __shared__ array (R9 lesson: separate
// __shared__ arrays have no guaranteed adjacency; an aliasing pointer that
// spans them is OOB under some layouts -> dropped writes/zero reads).

// phase 0: S = M*M -> T2 = 2S - I, Sbf = bf16(S)
__global__ __launch_bounds__(1024) void gemm_S_kernel(const ushort* __restrict__ Mbf,
                                                      ushort* __restrict__ Sbf,
                                                      float* __restrict__ out) {
    __shared__ __align__(16) ushort smem[2 * 64 * BKP];  // 67.6 KB
    ushort(*sA)[BKP] = (ushort(*)[BKP])smem;
    ushort(*sB)[BKP] = (ushort(*)[BKP])(smem + 64 * BKP);
    float* red = (float*)smem;  // 48 KB reduction region, within smem

    int tid = threadIdx.x;
    int brow = blockIdx.y * 64, bcol = blockIdx.x * 64;
    int r = tid >> 4, c0 = (tid & 15) * 16;
    int wid = tid >> 6, lane = tid & 63;
    int gid = wid >> 2, w4 = wid & 3;
    int wr = (w4 & 1) * 32, wc = (w4 >> 1) * 32;
    int fr = lane & 15, g = lane >> 4;

    const ushort* Arow = Mbf + (size_t)(brow + r) * NPTS;
    const ushort* Brow = Mbf + (size_t)(bcol + r) * NPTS;

    f32x4 acc[2][2] = {};
    float4 pa0 = *(const float4*)(Arow + c0);
    float4 pa1 = *(const float4*)(Arow + c0 + 8);
    float4 pb0 = *(const float4*)(Brow + c0);
    float4 pb1 = *(const float4*)(Brow + c0 + 8);

    const int NT = NPTS / 256;
    for (int t = 0; t < NT; ++t) {
        __syncthreads();
        *(float4*)&sA[r][c0] = pa0;
        *(float4*)&sA[r][c0 + 8] = pa1;
        *(float4*)&sB[r][c0] = pb0;
        *(float4*)&sB[r][c0 + 8] = pb1;
        __syncthreads();
        if (t + 1 < NT) {
            int k0 = (t + 1) * 256;
            pa0 = *(const float4*)(Arow + k0 + c0);
            pa1 = *(const float4*)(Arow + k0 + c0 + 8);
            pb0 = *(const float4*)(Brow + k0 + c0);
            pb1 = *(const float4*)(Brow + k0 + c0 + 8);
        }
#pragma unroll
        for (int kc = 0; kc < 2; ++kc) {
            int kk = gid * 64 + kc * 32 + g * 8;
            bf16x8 a0 = *(const bf16x8*)&sA[wr + fr][kk];
            bf16x8 a1 = *(const bf16x8*)&sA[wr + 16 + fr][kk];
            bf16x8 b0 = *(const bf16x8*)&sB[wc + fr][kk];
            bf16x8 b1 = *(const bf16x8*)&sB[wc + 16 + fr][kk];
            acc[0][0] = MFMA(a0, b0, acc[0][0]);
            acc[0][1] = MFMA(a0, b1, acc[0][1]);
            acc[1][0] = MFMA(a1, b0, acc[1][0]);
            acc[1][1] = MFMA(a1, b1, acc[1][1]);
        }
    }

    __syncthreads();
    if (gid > 0) {
#pragma unroll
        for (int q = 0; q < 4; ++q)
            *(f32x4*)&red[(gid - 1) * 4096 + q * 1024 + (w4 * 64 + lane) * 4] =
                acc[q >> 1][q & 1];
    }
    __syncthreads();
    if (gid == 0) {
        float* T2 = out + (size_t)2 * NN;
#pragma unroll
        for (int mi = 0; mi < 2; ++mi) {
#pragma unroll
            for (int ni = 0; ni < 2; ++ni) {
                int base = (mi * 2 + ni) * 1024 + (w4 * 64 + lane) * 4;
                f32x4 o1 = *(f32x4*)&red[base];
                f32x4 o2 = *(f32x4*)&red[4096 + base];
                f32x4 o3 = *(f32x4*)&red[8192 + base];
#pragma unroll
                for (int q = 0; q < 4; ++q) {
                    int row = brow + wr + mi * 16 + g * 4 + q;
                    int col = bcol + wc + ni * 16 + fr;
                    size_t idx = (size_t)row * NPTS + col;
                    float s = acc[mi][ni][q] + o1[q] + o2[q] + o3[q];
                    T2[idx] = 2.f * s - (row == col ? 1.f : 0.f);
                    Sbf[idx] = f2bf(s);
                }
            }
        }
    }
}

// phase 1 (fused): P = S*S -> T4 = 8P - 4*T2 - 3I;  R = M*S -> T3 = 4R - 3*T1
__global__ __launch_bounds__(1024) void gemm_T34_kernel(const ushort* __restrict__ Mbf,
                                                        const ushort* __restrict__ Sbf,
                                                        float* __restrict__ out,
                                                        int zimag) {
    // hidden zeroing of the imag half (20.9 MB over 256 blocks)
    if (zimag) {
        int bid = blockIdx.y * 16 + blockIdx.x;
        float4* z = (float4*)(out + (size_t)5 * NN) + (size_t)bid * 5120 + threadIdx.x;
#pragma unroll
        for (int i = 0; i < 5; ++i) z[i * 1024] = make_float4(0.f, 0.f, 0.f, 0.f);
    }

    __shared__ __align__(16) ushort smem[3 * 64 * BKP];  // 101.4 KB
    ushort(*sAS)[BKP] = (ushort(*)[BKP])smem;
    ushort(*sAM)[BKP] = (ushort(*)[BKP])(smem + 64 * BKP);
    ushort(*sB)[BKP] = (ushort(*)[BKP])(smem + 2 * 64 * BKP);
    float* redP = (float*)smem;          // 48 KB
    float* redR = redP + 3 * 4096;       // 48 KB, total 96 KB < 101.4 KB

    int tid = threadIdx.x;
    int brow = blockIdx.y * 64, bcol = blockIdx.x * 64;
    int r = tid >> 4, c0 = (tid & 15) * 16;
    int wid = tid >> 6, lane = tid & 63;
    int gid = wid >> 2, w4 = wid & 3;
    int wr = (w4 & 1) * 32, wc = (w4 >> 1) * 32;
    int fr = lane & 15, g = lane >> 4;

    const ushort* ASrow = Sbf + (size_t)(brow + r) * NPTS;
    const ushort* AMrow = Mbf + (size_t)(brow + r) * NPTS;
    const ushort* Brow = Sbf + (size_t)(bcol + r) * NPTS;

    f32x4 accP[2][2] = {};
    f32x4 accR[2][2] = {};
    float4 ps0 = *(const float4*)(ASrow + c0);
    float4 ps1 = *(const float4*)(ASrow + c0 + 8);
    float4 pm0 = *(const float4*)(AMrow + c0);
    float4 pm1 = *(const float4*)(AMrow + c0 + 8);
    float4 pb0 = *(const float4*)(Brow + c0);
    float4 pb1 = *(const float4*)(Brow + c0 + 8);

    const int NT = NPTS / 256;
    for (int t = 0; t < NT; ++t) {
        __syncthreads();
        *(float4*)&sAS[r][c0] = ps0;
        *(float4*)&sAS[r][c0 + 8] = ps1;
        *(float4*)&sAM[r][c0] = pm0;
        *(float4*)&sAM[r][c0 + 8] = pm1;
        *(float4*)&sB[r][c0] = pb0;
        *(float4*)&sB[r][c0 + 8] = pb1;
        __syncthreads();
        if (t + 1 < NT) {
            int k0 = (t + 1) * 256;
            ps0 = *(const float4*)(ASrow + k0 + c0);
            ps1 = *(const float4*)(ASrow + k0 + c0 + 8);
            pm0 = *(const float4*)(AMrow + k0 + c0);
            pm1 = *(const float4*)(AMrow + k0 + c0 + 8);
            pb0 = *(const float4*)(Brow + k0 + c0);
            pb1 = *(const float4*)(Brow + k0 + c0 + 8);
        }
#pragma unroll
        for (int kc = 0; kc < 2; ++kc) {
            int kk = gid * 64 + kc * 32 + g * 8;
            bf16x8 b0 = *(const bf16x8*)&sB[wc + fr][kk];
            bf16x8 b1 = *(const bf16x8*)&sB[wc + 16 + fr][kk];
            bf16x8 s0 = *(const bf16x8*)&sAS[wr + fr][kk];
            bf16x8 s1 = *(const bf16x8*)&sAS[wr + 16 + fr][kk];
            accP[0][0] = MFMA(s0, b0, accP[0][0]);
            accP[0][1] = MFMA(s0, b1, accP[0][1]);
            accP[1][0] = MFMA(s1, b0, accP[1][0]);
            accP[1][1] = MFMA(s1, b1, accP[1][1]);
            bf16x8 m0 = *(const bf16x8*)&sAM[wr + fr][kk];
            bf16x8 m1 = *(const bf16x8*)&sAM[wr + 16 + fr][kk];
            accR[0][0] = MFMA(m0, b0, accR[0][0]);
            accR[0][1] = MFMA(m0, b1, accR[0][1]);
            accR[1][0] = MFMA(m1, b0, accR[1][0]);
            accR[1][1] = MFMA(m1, b1, accR[1][1]);
        }
    }

    __syncthreads();
    if (gid > 0) {
#pragma unroll
        for (int q = 0; q < 4; ++q) {
            int base = (gid - 1) * 4096 + q * 1024 + (w4 * 64 + lane) * 4;
            *(f32x4*)&redP[base] = accP[q >> 1][q & 1];
            *(f32x4*)&redR[base] = accR[q >> 1][q & 1];
        }
    }
    __syncthreads();
    if (gid == 0) {
        float* T1 = out + (size_t)NN;
        float* T2 = out + (size_t)2 * NN;
        float* T3 = out + (size_t)3 * NN;
        float* T4 = out + (size_t)4 * NN;
#pragma unroll
        for (int mi = 0; mi < 2; ++mi) {
#pragma unroll
            for (int ni = 0; ni < 2; ++ni) {
                int base = (mi * 2 + ni) * 1024 + (w4 * 64 + lane) * 4;
                f32x4 p1 = *(f32x4*)&redP[base];
                f32x4 p2 = *(f32x4*)&redP[4096 + base];
                f32x4 p3 = *(f32x4*)&redP[8192 + base];
                f32x4 r1 = *(f32x4*)&redR[base];
                f32x4 r2 = *(f32x4*)&redR[4096 + base];
                f32x4 r3 = *(f32x4*)&redR[8192 + base];
#pragma unroll
                for (int q = 0; q < 4; ++q) {
                    int row = brow + wr + mi * 16 + g * 4 + q;
                    int col = bcol + wc + ni * 16 + fr;
                    size_t idx = (size_t)row * NPTS + col;
                    float sp = accP[mi][ni][q] + p1[q] + p2[q] + p3[q];
                    float sr = accR[mi][ni][q] + r1[q] + r2[q] + r3[q];
                    T4[idx] = 8.f * sp - 4.f * T2[idx] - (row == col ? 3.f : 0.f);
                    T3[idx] = 4.f * sr - 3.f * T1[idx];
                }
            }
        }
    }
}

__global__ void zero_kernel(float4* __restrict__ p, int n4) {
    int i = blockIdx.x * blockDim.x + threadIdx.x;
    if (i < n4) p[i] = make_float4(0.f, 0.f, 0.f, 0.f);
}

// ---------------- launch ----------------

extern "C" void kernel_launch(void* const* d_in, const int* in_sizes, int n_in,
                              void* d_out, int out_size, void* d_ws, size_t ws_size,
                              hipStream_t stream) {
    const float* feat = (const float*)d_in[0];
    const int* edges = (const int*)d_in[1];
    const float* w_e1 = (const float*)d_in[2];
    const float* b_e1 = (const float*)d_in[3];
    float* out = (float*)d_out;

    const size_t need = (size_t)NN * 4 + (size_t)NN * 2 + (size_t)NN * 2 + NPTS * 8 + 256;
    float* A;
    ushort* Mbf;
    ushort* Sbf;
    float* p;
    float* dd;
    int use_ws = (ws_size >= need);
    if (use_ws) {
        char* w = (char*)d_ws;
        A = (float*)w;        w += (size_t)NN * 4;
        Mbf = (ushort*)w;     w += (size_t)NN * 2;
        Sbf = (ushort*)w;     w += (size_t)NN * 2;
        p = (float*)w;        w += NPTS * 4;
        dd = (float*)w;
    } else {
        A = out + (size_t)5 * NN;
        Mbf = (ushort*)(out + (size_t)6 * NN);
        Sbf = Mbf + NN;
        p = out + (size_t)7 * NN;
        dd = p + NPTS;
    }

    zeroA_p_kernel<<<1024, 256, 0, stream>>>((float4*)A, feat, w_e1, b_e1, p, (float4*)dd);
    build_A_kernel<<<(NEDGE + 255) / 256, 256, 0, stream>>>(edges, edges + NEDGE, p, A, dd);
    normalize_kernel<<<NN / 4 / 256, 256, 0, stream>>>(A, dd, out, Mbf);

    dim3 grid(16, 16);
    gemm_S_kernel<<<grid, 1024, 0, stream>>>(Mbf, Sbf, out);
    gemm_T34_kernel<<<grid, 1024, 0, stream>>>(Mbf, Sbf, out, use_ws);

    if (!use_ws) {
        zero_kernel<<<(5 * NN / 4 + 255) / 256, 256, 0, stream>>>(
            (float4*)(out + (size_t)5 * NN), 5 * NN / 4);
    }
}

// Round 11
// 61.892 us; speedup vs baseline: 1.1209x; 1.0029x over previous
//
#include <hip/hip_runtime.h>

#define NPTS 1024
#define NN (NPTS * NPTS)
#define NEDGE 32768
#define INDIM 128
#define BKP 136  // 128 K + 8 pad (bf16 units)

typedef __attribute__((ext_vector_type(8))) short bf16x8;
typedef __attribute__((ext_vector_type(4))) float f32x4;

__device__ inline ushort f2bf(float x) {
    union { float f; unsigned u; } v; v.f = x;
    unsigned r = (v.u + 0x7FFF + ((v.u >> 16) & 1)) >> 16;
    return (ushort)r;
}

#define MFMA(a, b, c) __builtin_amdgcn_mfma_f32_16x16x32_bf16(a, b, c, 0, 0, 0)

// ---------------- front-end kernels (unchanged, proven) ----------------

__global__ void zeroA_p_kernel(float4* __restrict__ A4,
                               const float* __restrict__ feat,
                               const float* __restrict__ w,
                               const float* __restrict__ b,
                               float* __restrict__ p,
                               float4* __restrict__ dd4) {
    int t = threadIdx.x;
    A4[blockIdx.x * 256 + t] = make_float4(0.f, 0.f, 0.f, 0.f);
    if (blockIdx.x == 1023 && t < 256) dd4[t] = make_float4(0.f, 0.f, 0.f, 0.f);
    if (blockIdx.x < 256) {
        int wid = t >> 6, lane = t & 63;
        int node = blockIdx.x * 4 + wid;
        const float* f = feat + node * INDIM;
        float s = f[lane] * w[lane] + f[lane + 64] * w[lane + 64];
#pragma unroll
        for (int off = 32; off; off >>= 1) s += __shfl_down(s, off);
        if (lane == 0) p[node] = s + b[0];
    }
}

__global__ void build_A_kernel(const int* __restrict__ eu, const int* __restrict__ ev,
                               const float* __restrict__ p, float* __restrict__ A,
                               float* __restrict__ dd) {
    int i = blockIdx.x * blockDim.x + threadIdx.x;
    if (i >= NEDGE) return;
    int u = eu[i], v = ev[i];
    float val = p[u] - p[v];
    if (val > 0.f) {
        float w = 1.f + val;
        atomicAdd(&A[u * NPTS + v], w);
        atomicAdd(&A[v * NPTS + u], w);
        atomicAdd(&dd[u], w);
        atomicAdd(&dd[v], w);
    } else {
        atomicAdd(&A[u * NPTS + u], 1.f);
        atomicAdd(&A[v * NPTS + v], 1.f);
        atomicAdd(&dd[u], 1.f);
        atomicAdd(&dd[v], 1.f);
    }
}

__global__ void normalize_kernel(const float* __restrict__ A, const float* __restrict__ dd,
                                 float* __restrict__ out, ushort* __restrict__ Mbf) {
    int idx4 = blockIdx.x * blockDim.x + threadIdx.x;
    int i = idx4 >> 8;
    int j = (idx4 & 255) * 4;
    size_t idx = (size_t)idx4 * 4;
    float di = rsqrtf(dd[i] + 1.f);
    float4 a = *(const float4*)(A + idx);
    float4 d4 = *(const float4*)(dd + j);
    float4 t0 = make_float4(0.f, 0.f, 0.f, 0.f);
    if (i == j) t0.x = 1.f;
    else if (i == j + 1) t0.y = 1.f;
    else if (i == j + 2) t0.z = 1.f;
    else if (i == j + 3) t0.w = 1.f;
    a.x += (i == j);
    a.y += (i == j + 1);
    a.z += (i == j + 2);
    a.w += (i == j + 3);
    float4 m;
    m.x = -(di * a.x * rsqrtf(d4.x + 1.f));
    m.y = -(di * a.y * rsqrtf(d4.y + 1.f));
    m.z = -(di * a.z * rsqrtf(d4.z + 1.f));
    m.w = -(di * a.w * rsqrtf(d4.w + 1.f));
    *(float4*)(out + idx) = t0;
    *(float4*)(out + NN + idx) = m;
    ushort mb[4] = {f2bf(m.x), f2bf(m.y), f2bf(m.z), f2bf(m.w)};
    *(uint2*)(Mbf + idx) = *(uint2*)mb;
}

// ---------------- MFMA GEMMs ----------------
// NEW GEOMETRY: 32x64 tile / block, grid 512 blocks = 2 INDEPENDENT blocks
// per CU (every prior round had exactly 1 barrier domain/CU; this is the one
// untested lever). 256 thr = 4 waves; wave owns 16x32: wr=(wid&1)*16,
// wc=(wid>>1)*32. BK=128, 8 iters, proven 2-barrier skeleton.
// LDS: gemm_S 26 KB, gemm_T34 35 KB -> 2 blocks/CU resident.

// phase 0: S = M*M -> T2 = 2S - I, Sbf = bf16(S)
__global__ void gemm_S_kernel(const ushort* __restrict__ Mbf,
                              ushort* __restrict__ Sbf,
                              float* __restrict__ out) {
    __shared__ __align__(16) ushort smem[(32 + 64) * BKP];  // 25.5 KB
    ushort(*sA)[BKP] = (ushort(*)[BKP])smem;                // 32 x BKP
    ushort(*sB)[BKP] = (ushort(*)[BKP])(smem + 32 * BKP);   // 64 x BKP

    int tid = threadIdx.x;
    int brow = blockIdx.y * 32, bcol = blockIdx.x * 64;
    int ra = tid >> 3, ca = (tid & 7) * 16;   // A: 32 rows x 128, 2 float4/thr
    int rb = tid >> 2, cb = (tid & 3) * 32;   // B: 64 rows x 128, 4 float4/thr
    int wid = tid >> 6, lane = tid & 63;
    int wr = (wid & 1) * 16, wc = (wid >> 1) * 32;
    int fr = lane & 15, g = lane >> 4;

    const ushort* Arow = Mbf + (size_t)(brow + ra) * NPTS + ca;
    const ushort* Brow = Mbf + (size_t)(bcol + rb) * NPTS + cb;

    f32x4 acc[2] = {};
    float4 pa0 = *(const float4*)(Arow);
    float4 pa1 = *(const float4*)(Arow + 8);
    float4 pb0 = *(const float4*)(Brow);
    float4 pb1 = *(const float4*)(Brow + 8);
    float4 pb2 = *(const float4*)(Brow + 16);
    float4 pb3 = *(const float4*)(Brow + 24);

    const int NT = NPTS / 128;
    for (int t = 0; t < NT; ++t) {
        __syncthreads();
        *(float4*)&sA[ra][ca] = pa0;
        *(float4*)&sA[ra][ca + 8] = pa1;
        *(float4*)&sB[rb][cb] = pb0;
        *(float4*)&sB[rb][cb + 8] = pb1;
        *(float4*)&sB[rb][cb + 16] = pb2;
        *(float4*)&sB[rb][cb + 24] = pb3;
        __syncthreads();
        if (t + 1 < NT) {
            int k0 = (t + 1) * 128;
            pa0 = *(const float4*)(Arow + k0);
            pa1 = *(const float4*)(Arow + k0 + 8);
            pb0 = *(const float4*)(Brow + k0);
            pb1 = *(const float4*)(Brow + k0 + 8);
            pb2 = *(const float4*)(Brow + k0 + 16);
            pb3 = *(const float4*)(Brow + k0 + 24);
        }
#pragma unroll
        for (int kc = 0; kc < 4; ++kc) {
            int kk = kc * 32 + g * 8;
            bf16x8 a0 = *(const bf16x8*)&sA[wr + fr][kk];
            bf16x8 b0 = *(const bf16x8*)&sB[wc + fr][kk];
            bf16x8 b1 = *(const bf16x8*)&sB[wc + 16 + fr][kk];
            acc[0] = MFMA(a0, b0, acc[0]);
            acc[1] = MFMA(a0, b1, acc[1]);
        }
    }

    float* T2 = out + (size_t)2 * NN;
#pragma unroll
    for (int ni = 0; ni < 2; ++ni) {
#pragma unroll
        for (int q = 0; q < 4; ++q) {
            int row = brow + wr + g * 4 + q;
            int col = bcol + wc + ni * 16 + fr;
            size_t idx = (size_t)row * NPTS + col;
            float s = acc[ni][q];
            T2[idx] = 2.f * s - (row == col ? 1.f : 0.f);
            Sbf[idx] = f2bf(s);
        }
    }
}

// phase 1 (fused): P = S*S -> T4 = 8P - 4*T2 - 3I;  R = M*S -> T3 = 4R - 3*T1
__global__ void gemm_T34_kernel(const ushort* __restrict__ Mbf,
                                const ushort* __restrict__ Sbf,
                                float* __restrict__ out,
                                int zimag) {
    // hidden zeroing of the imag half (20.9 MB over 512 blocks)
    if (zimag) {
        int bid = blockIdx.y * 16 + blockIdx.x;
        float4* z = (float4*)(out + (size_t)5 * NN) + (size_t)bid * 2560 + threadIdx.x;
#pragma unroll
        for (int i = 0; i < 10; ++i) z[i * 256] = make_float4(0.f, 0.f, 0.f, 0.f);
    }

    __shared__ __align__(16) ushort smem[(32 + 32 + 64) * BKP];  // 34 KB
    ushort(*sAS)[BKP] = (ushort(*)[BKP])smem;
    ushort(*sAM)[BKP] = (ushort(*)[BKP])(smem + 32 * BKP);
    ushort(*sB)[BKP] = (ushort(*)[BKP])(smem + 64 * BKP);

    int tid = threadIdx.x;
    int brow = blockIdx.y * 32, bcol = blockIdx.x * 64;
    int ra = tid >> 3, ca = (tid & 7) * 16;
    int rb = tid >> 2, cb = (tid & 3) * 32;
    int wid = tid >> 6, lane = tid & 63;
    int wr = (wid & 1) * 16, wc = (wid >> 1) * 32;
    int fr = lane & 15, g = lane >> 4;

    const ushort* ASrow = Sbf + (size_t)(brow + ra) * NPTS + ca;
    const ushort* AMrow = Mbf + (size_t)(brow + ra) * NPTS + ca;
    const ushort* Brow = Sbf + (size_t)(bcol + rb) * NPTS + cb;

    f32x4 accP[2] = {};
    f32x4 accR[2] = {};
    float4 ps0 = *(const float4*)(ASrow);
    float4 ps1 = *(const float4*)(ASrow + 8);
    float4 pm0 = *(const float4*)(AMrow);
    float4 pm1 = *(const float4*)(AMrow + 8);
    float4 pb0 = *(const float4*)(Brow);
    float4 pb1 = *(const float4*)(Brow + 8);
    float4 pb2 = *(const float4*)(Brow + 16);
    float4 pb3 = *(const float4*)(Brow + 24);

    const int NT = NPTS / 128;
    for (int t = 0; t < NT; ++t) {
        __syncthreads();
        *(float4*)&sAS[ra][ca] = ps0;
        *(float4*)&sAS[ra][ca + 8] = ps1;
        *(float4*)&sAM[ra][ca] = pm0;
        *(float4*)&sAM[ra][ca + 8] = pm1;
        *(float4*)&sB[rb][cb] = pb0;
        *(float4*)&sB[rb][cb + 8] = pb1;
        *(float4*)&sB[rb][cb + 16] = pb2;
        *(float4*)&sB[rb][cb + 24] = pb3;
        __syncthreads();
        if (t + 1 < NT) {
            int k0 = (t + 1) * 128;
            ps0 = *(const float4*)(ASrow + k0);
            ps1 = *(const float4*)(ASrow + k0 + 8);
            pm0 = *(const float4*)(AMrow + k0);
            pm1 = *(const float4*)(AMrow + k0 + 8);
            pb0 = *(const float4*)(Brow + k0);
            pb1 = *(const float4*)(Brow + k0 + 8);
            pb2 = *(const float4*)(Brow + k0 + 16);
            pb3 = *(const float4*)(Brow + k0 + 24);
        }
#pragma unroll
        for (int kc = 0; kc < 4; ++kc) {
            int kk = kc * 32 + g * 8;
            bf16x8 b0 = *(const bf16x8*)&sB[wc + fr][kk];
            bf16x8 b1 = *(const bf16x8*)&sB[wc + 16 + fr][kk];
            bf16x8 s0 = *(const bf16x8*)&sAS[wr + fr][kk];
            bf16x8 m0 = *(const bf16x8*)&sAM[wr + fr][kk];
            accP[0] = MFMA(s0, b0, accP[0]);
            accP[1] = MFMA(s0, b1, accP[1]);
            accR[0] = MFMA(m0, b0, accR[0]);
            accR[1] = MFMA(m0, b1, accR[1]);
        }
    }

    float* T1 = out + (size_t)NN;
    float* T2 = out + (size_t)2 * NN;
    float* T3 = out + (size_t)3 * NN;
    float* T4 = out + (size_t)4 * NN;
#pragma unroll
    for (int ni = 0; ni < 2; ++ni) {
#pragma unroll
        for (int q = 0; q < 4; ++q) {
            int row = brow + wr + g * 4 + q;
            int col = bcol + wc + ni * 16 + fr;
            size_t idx = (size_t)row * NPTS + col;
            float sp = accP[ni][q];
            float sr = accR[ni][q];
            T4[idx] = 8.f * sp - 4.f * T2[idx] - (row == col ? 3.f : 0.f);
            T3[idx] = 4.f * sr - 3.f * T1[idx];
        }
    }
}

__global__ void zero_kernel(float4* __restrict__ p, int n4) {
    int i = blockIdx.x * blockDim.x + threadIdx.x;
    if (i < n4) p[i] = make_float4(0.f, 0.f, 0.f, 0.f);
}

// ---------------- launch ----------------

extern "C" void kernel_launch(void* const* d_in, const int* in_sizes, int n_in,
                              void* d_out, int out_size, void* d_ws, size_t ws_size,
                              hipStream_t stream) {
    const float* feat = (const float*)d_in[0];
    const int* edges = (const int*)d_in[1];
    const float* w_e1 = (const float*)d_in[2];
    const float* b_e1 = (const float*)d_in[3];
    float* out = (float*)d_out;

    const size_t need = (size_t)NN * 4 + (size_t)NN * 2 + (size_t)NN * 2 + NPTS * 8 + 256;
    float* A;
    ushort* Mbf;
    ushort* Sbf;
    float* p;
    float* dd;
    int use_ws = (ws_size >= need);
    if (use_ws) {
        char* w = (char*)d_ws;
        A = (float*)w;        w += (size_t)NN * 4;
        Mbf = (ushort*)w;     w += (size_t)NN * 2;
        Sbf = (ushort*)w;     w += (size_t)NN * 2;
        p = (float*)w;        w += NPTS * 4;
        dd = (float*)w;
    } else {
        A = out + (size_t)5 * NN;
        Mbf = (ushort*)(out + (size_t)6 * NN);
        Sbf = Mbf + NN;
        p = out + (size_t)7 * NN;
        dd = p + NPTS;
    }

    zeroA_p_kernel<<<1024, 256, 0, stream>>>((float4*)A, feat, w_e1, b_e1, p, (float4*)dd);
    build_A_kernel<<<(NEDGE + 255) / 256, 256, 0, stream>>>(edges, edges + NEDGE, p, A, dd);
    normalize_kernel<<<NN / 4 / 256, 256, 0, stream>>>(A, dd, out, Mbf);

    dim3 grid(16, 32);  // 512 blocks = 2 independent blocks/CU
    gemm_S_kernel<<<grid, 256, 0, stream>>>(Mbf, Sbf, out);
    gemm_T34_kernel<<<grid, 256, 0, stream>>>(Mbf, Sbf, out, use_ws);

    if (!use_ws) {
        zero_kernel<<<(5 * NN / 4 + 255) / 256, 256, 0, stream>>>(
            (float4*)(out + (size_t)5 * NN), 5 * NN / 4);
    }
}